// Round 1
// baseline (2448.339 us; speedup 1.0000x reference)
//
#include <hip/hip_runtime.h>
#include <math.h>

constexpr int kBatch = 2;
constexpr int kS     = 2048;
constexpr int kHid   = 2048;
constexpr int kNH    = 16;
constexpr int kNKV   = 4;
constexpr int kHD    = 128;
constexpr int kM     = kBatch * kS;              // 4096 GEMM rows
constexpr int kNqkv  = kNH*kHD + 2*kNKV*kHD;     // 3072 = 2048 Q + 512 K + 512 V
constexpr float kScale = 0.08838834764831845f;   // 1/sqrt(128)

constexpr int BM = 64, BN = 64, BK = 16;

// C = A @ W^T (+bias), A: M x 2048 row-major, W rows are 2048-long.
// QKV variant scatters into head-major Q[B][NH][S][HD], K/V[B][NKV][S][HD].
__global__ __launch_bounds__(256)
void qkv_gemm_kernel(const float* __restrict__ hs,
                     const float* __restrict__ q_w, const float* __restrict__ q_b,
                     const float* __restrict__ k_w, const float* __restrict__ k_b,
                     const float* __restrict__ v_w, const float* __restrict__ v_b,
                     float* __restrict__ Q, float* __restrict__ K, float* __restrict__ V) {
  __shared__ __align__(16) float As[BK][BM];
  __shared__ __align__(16) float Ws[BK][BN];
  const int t  = threadIdx.x;
  const int m0 = blockIdx.x * BM;
  const int n0 = blockIdx.y * BN;
  const int lrow = t >> 2;           // 0..63: tile row this thread loads
  const int lkq  = (t & 3) << 2;     // k-quad within BK
  const int gn = n0 + lrow;
  const float* wrow;                 // region boundaries (2048,2560) are multiples of 64
  if (gn < 2048)      wrow = q_w + (size_t)gn * kHid;
  else if (gn < 2560) wrow = k_w + (size_t)(gn - 2048) * kHid;
  else                wrow = v_w + (size_t)(gn - 2560) * kHid;
  const float* arow = hs + (size_t)(m0 + lrow) * kHid;
  const int tm = (t & 15) << 2;
  const int tn = (t >> 4) << 2;
  float acc[4][4] = {{0.f}};
  for (int k0 = 0; k0 < kHid; k0 += BK) {
    const float4 av = *(const float4*)(arow + k0 + lkq);
    const float4 wv = *(const float4*)(wrow + k0 + lkq);
    __syncthreads();
    As[lkq+0][lrow] = av.x; As[lkq+1][lrow] = av.y;
    As[lkq+2][lrow] = av.z; As[lkq+3][lrow] = av.w;
    Ws[lkq+0][lrow] = wv.x; Ws[lkq+1][lrow] = wv.y;
    Ws[lkq+2][lrow] = wv.z; Ws[lkq+3][lrow] = wv.w;
    __syncthreads();
#pragma unroll
    for (int kk = 0; kk < BK; ++kk) {
      const float4 a = *(const float4*)&As[kk][tm];
      const float4 b = *(const float4*)&Ws[kk][tn];
      acc[0][0] += a.x*b.x; acc[0][1] += a.x*b.y; acc[0][2] += a.x*b.z; acc[0][3] += a.x*b.w;
      acc[1][0] += a.y*b.x; acc[1][1] += a.y*b.y; acc[1][2] += a.y*b.z; acc[1][3] += a.y*b.w;
      acc[2][0] += a.z*b.x; acc[2][1] += a.z*b.y; acc[2][2] += a.z*b.z; acc[2][3] += a.z*b.w;
      acc[3][0] += a.w*b.x; acc[3][1] += a.w*b.y; acc[3][2] += a.w*b.z; acc[3][3] += a.w*b.w;
    }
  }
#pragma unroll
  for (int i = 0; i < 4; ++i) {
    const int m = m0 + tm + i;
    const int b = m >> 11;           // m / S
    const int s = m & (kS - 1);
#pragma unroll
    for (int j = 0; j < 4; ++j) {
      const int n = n0 + tn + j;
      const float v = acc[i][j];
      if (n < 2048) {
        const int h = n >> 7, d = n & 127;
        Q[(((size_t)(b*kNH + h))*kS + s)*kHD + d] = v + q_b[n];
      } else if (n < 2560) {
        const int nk = n - 2048; const int h = nk >> 7, d = nk & 127;
        K[(((size_t)(b*kNKV + h))*kS + s)*kHD + d] = v + k_b[nk];
      } else {
        const int nk = n - 2560; const int h = nk >> 7, d = nk & 127;
        V[(((size_t)(b*kNKV + h))*kS + s)*kHD + d] = v + v_b[nk];
      }
    }
  }
}

// In-place RoPE on Q (heads 0..15) and K (heads 16..19). Pair (d, d+64), angle = s * theta^(-d/64).
__global__ __launch_bounds__(256)
void rope_kernel(float* __restrict__ Q, float* __restrict__ K) {
  const int t = threadIdx.x;
  const int s = blockIdx.x * 4 + (t >> 6);
  const int d = t & 63;
  const int head = blockIdx.y;
  const int b = blockIdx.z;
  float* row = (head < kNH)
      ? Q + (((size_t)(b*kNH + head))*kS + s)*kHD
      : K + (((size_t)(b*kNKV + (head - kNH)))*kS + s)*kHD;
  const float inv_freq = powf(10000.0f, -(float)d * (1.0f/64.0f));
  const float ang = (float)s * inv_freq;
  const float c = cosf(ang), sn = sinf(ang);
  const float x1 = row[d], x2 = row[d + 64];
  row[d]      = x1*c - x2*sn;
  row[d + 64] = x2*c + x1*sn;
}

// Flash attention, fp32. Block = 256 threads, TQ=32 q-rows, k-tiles of TK=64.
// Thread t: row r=t/8, col-lane cl=t%8 (8 lanes/row, row group = 8 contiguous lanes in one wave).
constexpr int TQ = 32, TK = 64;
constexpr int KSTR = 132;   // 128 + 4 pad: breaks bank aliasing, keeps 16B row alignment (528%16==0)
constexpr int SSTR = 72;    // 64 + 8 pad: bank = (t + 8*jj) % 32 on score writes

__global__ __launch_bounds__(256)
void flash_attn_kernel(const float* __restrict__ Q, const float* __restrict__ K,
                       const float* __restrict__ V, float* __restrict__ ctx) {
  __shared__ __align__(16) float Qs[TQ][KSTR];
  __shared__ __align__(16) float KVs[TK][KSTR];
  __shared__ float Ss[TQ][SSTR];
  const int t  = threadIdx.x;
  const int q0 = blockIdx.x * TQ;
  const int bh = blockIdx.y;
  const int b  = bh >> 4;
  const int h  = bh & 15;
  const int hk = h >> 2;               // GQA: 4 q-heads per kv-head
  const float* Qbase = Q + ((size_t)bh * kS + q0) * kHD;
  const float* Kbase = K + ((size_t)(b*kNKV + hk) * kS) * kHD;
  const float* Vbase = V + ((size_t)(b*kNKV + hk) * kS) * kHD;

#pragma unroll
  for (int it = 0; it < 4; ++it) {     // Q tile: 32x128 = 1024 float4
    const int f4 = t + it*256;
    const int rr = f4 >> 5;
    const int cq = (f4 & 31) << 2;
    *(float4*)&Qs[rr][cq] = *(const float4*)(Qbase + (size_t)rr*kHD + cq);
  }

  const int r  = t >> 3;
  const int cl = t & 7;
  const int qr = q0 + r;
  float mrow = -1e30f, lsum = 0.f;
  float4 o[4];
#pragma unroll
  for (int j = 0; j < 4; ++j) o[j] = make_float4(0.f, 0.f, 0.f, 0.f);

  const int ntiles = (q0 + TQ - 1)/TK + 1;   // causal: only tiles with k0 <= q0+TQ-1
  for (int kt = 0; kt < ntiles; ++kt) {
    const int k0 = kt * TK;
    __syncthreads();                   // prev O-update reads of KVs done
#pragma unroll
    for (int it = 0; it < 8; ++it) {   // K tile: 64x128
      const int f4 = t + it*256;
      const int rr = f4 >> 5;
      const int cq = (f4 & 31) << 2;
      *(float4*)&KVs[rr][cq] = *(const float4*)(Kbase + (size_t)(k0+rr)*kHD + cq);
    }
    __syncthreads();
    float sc[8];
#pragma unroll
    for (int jj = 0; jj < 8; ++jj) sc[jj] = 0.f;
    for (int kq = 0; kq < kHD; kq += 4) {
      const float4 qv = *(const float4*)&Qs[r][kq];       // broadcast across row group
#pragma unroll
      for (int jj = 0; jj < 8; ++jj) {                    // cols cl + 8*jj -> conflict-free b128
        const float4 kv = *(const float4*)&KVs[cl + (jj<<3)][kq];
        sc[jj] += qv.x*kv.x + qv.y*kv.y + qv.z*kv.z + qv.w*kv.w;
      }
    }
    float mt = -1e30f;
#pragma unroll
    for (int jj = 0; jj < 8; ++jj) {
      sc[jj] *= kScale;
      if (k0 + cl + (jj<<3) > qr) sc[jj] = -1e30f;        // causal mask
      mt = fmaxf(mt, sc[jj]);
    }
    mt = fmaxf(mt, __shfl_xor(mt, 1));                    // reduce over 8-lane row group
    mt = fmaxf(mt, __shfl_xor(mt, 2));
    mt = fmaxf(mt, __shfl_xor(mt, 4));
    const float mnew  = fmaxf(mrow, mt);
    const float alpha = __expf(mrow - mnew);              // ==1 when both -1e30 (O still 0)
    float ps = 0.f;
#pragma unroll
    for (int jj = 0; jj < 8; ++jj) {
      float p = __expf(sc[jj] - mnew);
      if (sc[jj] <= -1e29f) p = 0.f;                      // guard fully-masked tiles
      Ss[r][cl + (jj<<3)] = p;
      ps += p;
    }
    ps += __shfl_xor(ps, 1);
    ps += __shfl_xor(ps, 2);
    ps += __shfl_xor(ps, 4);
    lsum = lsum * alpha + ps;
    mrow = mnew;
    __syncthreads();                   // Ss visible; K reads done before V overwrite
#pragma unroll
    for (int it = 0; it < 8; ++it) {   // V tile overwrites K tile buffer
      const int f4 = t + it*256;
      const int rr = f4 >> 5;
      const int cq = (f4 & 31) << 2;
      *(float4*)&KVs[rr][cq] = *(const float4*)(Vbase + (size_t)(k0+rr)*kHD + cq);
    }
    __syncthreads();
#pragma unroll
    for (int j = 0; j < 4; ++j) { o[j].x *= alpha; o[j].y *= alpha; o[j].z *= alpha; o[j].w *= alpha; }
    for (int c = 0; c < TK; ++c) {
      const float p = Ss[r][c];                           // broadcast per row group
#pragma unroll
      for (int j = 0; j < 4; ++j) {    // thread owns cols cl*4 + 32j (+0..3): conflict-free b128
        const float4 vv = *(const float4*)&KVs[c][(cl<<2) + (j<<5)];
        o[j].x += p*vv.x; o[j].y += p*vv.y; o[j].z += p*vv.z; o[j].w += p*vv.w;
      }
    }
  }
  const float invl = 1.0f / lsum;
  float* orow = ctx + ((size_t)(b*kS + qr))*(kNH*kHD) + h*kHD;
#pragma unroll
  for (int j = 0; j < 4; ++j) {
    const int vc = (cl<<2) + (j<<5);
    float4 vv;
    vv.x = o[j].x*invl; vv.y = o[j].y*invl; vv.z = o[j].z*invl; vv.w = o[j].w*invl;
    *(float4*)(orow + vc) = vv;
  }
}

// out = ctx @ o_w^T, plain BT GEMM, writes d_out row-major (B*S, 2048)
__global__ __launch_bounds__(256)
void oproj_gemm_kernel(const float* __restrict__ A, const float* __restrict__ W,
                       float* __restrict__ C) {
  __shared__ __align__(16) float As[BK][BM];
  __shared__ __align__(16) float Ws[BK][BN];
  const int t  = threadIdx.x;
  const int m0 = blockIdx.x * BM;
  const int n0 = blockIdx.y * BN;
  const int lrow = t >> 2;
  const int lkq  = (t & 3) << 2;
  const float* wrow = W + (size_t)(n0 + lrow) * kHid;
  const float* arow = A + (size_t)(m0 + lrow) * kHid;
  const int tm = (t & 15) << 2;
  const int tn = (t >> 4) << 2;
  float acc[4][4] = {{0.f}};
  for (int k0 = 0; k0 < kHid; k0 += BK) {
    const float4 av = *(const float4*)(arow + k0 + lkq);
    const float4 wv = *(const float4*)(wrow + k0 + lkq);
    __syncthreads();
    As[lkq+0][lrow] = av.x; As[lkq+1][lrow] = av.y;
    As[lkq+2][lrow] = av.z; As[lkq+3][lrow] = av.w;
    Ws[lkq+0][lrow] = wv.x; Ws[lkq+1][lrow] = wv.y;
    Ws[lkq+2][lrow] = wv.z; Ws[lkq+3][lrow] = wv.w;
    __syncthreads();
#pragma unroll
    for (int kk = 0; kk < BK; ++kk) {
      const float4 a = *(const float4*)&As[kk][tm];
      const float4 b = *(const float4*)&Ws[kk][tn];
      acc[0][0] += a.x*b.x; acc[0][1] += a.x*b.y; acc[0][2] += a.x*b.z; acc[0][3] += a.x*b.w;
      acc[1][0] += a.y*b.x; acc[1][1] += a.y*b.y; acc[1][2] += a.y*b.z; acc[1][3] += a.y*b.w;
      acc[2][0] += a.z*b.x; acc[2][1] += a.z*b.y; acc[2][2] += a.z*b.z; acc[2][3] += a.z*b.w;
      acc[3][0] += a.w*b.x; acc[3][1] += a.w*b.y; acc[3][2] += a.w*b.z; acc[3][3] += a.w*b.w;
    }
  }
#pragma unroll
  for (int i = 0; i < 4; ++i) {
    const int m = m0 + tm + i;
#pragma unroll
    for (int j = 0; j < 4; ++j) {
      C[(size_t)m * kHid + (n0 + tn + j)] = acc[i][j];
    }
  }
}

extern "C" void kernel_launch(void* const* d_in, const int* in_sizes, int n_in,
                              void* d_out, int out_size, void* d_ws, size_t ws_size,
                              hipStream_t stream) {
  const float* hs  = (const float*)d_in[0];
  // d_in[1] = attention_mask: known causal, not read
  const float* q_w = (const float*)d_in[2];
  const float* q_b = (const float*)d_in[3];
  const float* k_w = (const float*)d_in[4];
  const float* k_b = (const float*)d_in[5];
  const float* v_w = (const float*)d_in[6];
  const float* v_b = (const float*)d_in[7];
  const float* o_w = (const float*)d_in[8];

  // Q lives in d_out (same 8M-float size); fully consumed by flash_attn before oproj overwrites d_out.
  float* Q   = (float*)d_out;
  float* ws  = (float*)d_ws;
  const size_t kvElems = (size_t)kBatch * kNKV * kS * kHD;   // 2,097,152 floats
  float* K   = ws;
  float* V   = ws + kvElems;
  float* ctx = ws + 2*kvElems;                               // 8,388,608 floats; total ws use = 48 MB

  dim3 gq(kM/BM, kNqkv/BN);            // 64 x 48
  qkv_gemm_kernel<<<gq, dim3(256), 0, stream>>>(hs, q_w, q_b, k_w, k_b, v_w, v_b, Q, K, V);

  dim3 gr(kS/4, kNH + kNKV, kBatch);   // 512 x 20 x 2, 4 rows/block
  rope_kernel<<<gr, dim3(256), 0, stream>>>(Q, K);

  dim3 ga(kS/TQ, kBatch*kNH);          // 64 x 32
  flash_attn_kernel<<<ga, dim3(256), 0, stream>>>(Q, K, V, ctx);

  dim3 go(kM/BM, kHid/BN);             // 64 x 32
  oproj_gemm_kernel<<<go, dim3(256), 0, stream>>>(ctx, o_w, (float*)d_out);
}

// Round 2
// 555.357 us; speedup vs baseline: 4.4086x; 4.4086x over previous
//
#include <hip/hip_runtime.h>
#include <math.h>

typedef __attribute__((ext_vector_type(8))) short bf16x8;   // 8 bf16 in 4 VGPRs
typedef __attribute__((ext_vector_type(4))) float f32x4;
typedef unsigned short u16;

constexpr int kB = 2, kS = 2048, kHid = 2048, kNH = 16, kNKV = 4, kHD = 128;
constexpr float kScale = 0.08838834764831845f;   // 1/sqrt(128)

__device__ __forceinline__ u16 f2bf(float x) {
  union { float f; unsigned int u; } v; v.f = x;
  unsigned int r = v.u + 0x7fffu + ((v.u >> 16) & 1u);   // RNE
  return (u16)(r >> 16);
}
__device__ __forceinline__ float bf2f(u16 b) {
  union { unsigned int u; float f; } v; v.u = ((unsigned int)b) << 16;
  return v.f;
}
__device__ __forceinline__ void gl_lds16(const u16* g, u16* l) {
  __builtin_amdgcn_global_load_lds((const __attribute__((address_space(1))) void*)g,
                                   (__attribute__((address_space(3))) void*)l, 16, 0, 0);
}

// ---------------- fp32 -> bf16 conversion, 8 elements/thread ----------------
__global__ __launch_bounds__(256)
void conv_bf16(const float* __restrict__ s, u16* __restrict__ d, int n8) {
  int i = blockIdx.x * 256 + threadIdx.x;
  if (i >= n8) return;
  const float4* s4 = (const float4*)s;
  float4 a = s4[2*i], b = s4[2*i + 1];
  __align__(16) u16 tmp[8] = {f2bf(a.x), f2bf(a.y), f2bf(a.z), f2bf(a.w),
                              f2bf(b.x), f2bf(b.y), f2bf(b.z), f2bf(b.w)};
  *(uint4*)(d + 8*(size_t)i) = *(const uint4*)tmp;
}

// ---------------- QKV projection: bf16 MFMA GEMM, 128x128 tile, BK=32 -------
// C[m][n] = sum_k hs[m][k]*W[n][k] (+bias); scatter: Q head-major, K head-major,
// V TRANSPOSED [b][hk][d][s] so flash PV B-fragments are contiguous.
__global__ __launch_bounds__(256)
void qkv_mfma(const u16* __restrict__ hs_b,
              const u16* __restrict__ qw_b, const u16* __restrict__ kw_b,
              const u16* __restrict__ vw_b,
              const float* __restrict__ q_bias, const float* __restrict__ k_bias,
              const float* __restrict__ v_bias,
              u16* __restrict__ Qb, u16* __restrict__ Kb, u16* __restrict__ Vbt) {
  __shared__ u16 At[128*32];
  __shared__ u16 Bt[128*32];
  const int t = threadIdx.x, w = t >> 6, lane = t & 63;
  const int quad = lane >> 4, cl = lane & 15;
  const int wm = w >> 1, wn = w & 1;
  const int m0 = blockIdx.x * 128, n0 = blockIdx.y * 128;
  const u16* wbase; int nr0;                 // region (128-aligned boundaries)
  if (n0 < 2048)      { wbase = qw_b; nr0 = n0; }
  else if (n0 < 2560) { wbase = kw_b; nr0 = n0 - 2048; }
  else                { wbase = vw_b; nr0 = n0 - 2560; }

  const int srow = lane >> 2;                // 0..15 in 16-row chunk
  const int scol = (lane & 3) * 8;           // bf16 col offset (16B granules)

  f32x4 acc[4][4];
#pragma unroll
  for (int i = 0; i < 4; ++i)
#pragma unroll
    for (int j = 0; j < 4; ++j) acc[i][j] = f32x4{0.f, 0.f, 0.f, 0.f};

  for (int k0 = 0; k0 < kHid; k0 += 32) {
    __syncthreads();                          // frag reads of prev iter done
#pragma unroll
    for (int c = 0; c < 2; ++c) {
      const int rr = w*32 + c*16;
      gl_lds16(hs_b  + (size_t)(m0 + rr + srow)*kHid + k0 + scol, At + rr*32);
      gl_lds16(wbase + (size_t)(nr0 + rr + srow)*kHid + k0 + scol, Bt + rr*32);
    }
    __syncthreads();                          // vmcnt(0) drained by compiler
    bf16x8 a[4], b[4];
#pragma unroll
    for (int i = 0; i < 4; ++i)
      a[i] = *(const bf16x8*)(At + (wm*64 + i*16 + cl)*32 + quad*8);
#pragma unroll
    for (int j = 0; j < 4; ++j)
      b[j] = *(const bf16x8*)(Bt + (wn*64 + j*16 + cl)*32 + quad*8);
#pragma unroll
    for (int i = 0; i < 4; ++i)
#pragma unroll
      for (int j = 0; j < 4; ++j)
        acc[i][j] = __builtin_amdgcn_mfma_f32_16x16x32_bf16(a[i], b[j], acc[i][j], 0, 0, 0);
  }
  // epilogue: C row = m0+wm*64+i*16+quad*4+r, col = n0+wn*64+j*16+cl
#pragma unroll
  for (int i = 0; i < 4; ++i) {
#pragma unroll
    for (int r = 0; r < 4; ++r) {
      const int m = m0 + wm*64 + i*16 + quad*4 + r;
      const int bi = m >> 11, s = m & (kS - 1);
#pragma unroll
      for (int j = 0; j < 4; ++j) {
        const int n = n0 + wn*64 + j*16 + cl;
        float v = acc[i][j][r];
        if (n < 2048) {
          v += q_bias[n];
          Qb[(((size_t)(bi*kNH + (n >> 7)))*kS + s)*kHD + (n & 127)] = f2bf(v);
        } else if (n < 2560) {
          const int nk = n - 2048; v += k_bias[nk];
          Kb[(((size_t)(bi*kNKV + (nk >> 7)))*kS + s)*kHD + (nk & 127)] = f2bf(v);
        } else {
          const int nk = n - 2560; v += v_bias[nk];
          Vbt[(((size_t)(bi*kNKV + (nk >> 7)))*kHD + (nk & 127))*kS + s] = f2bf(v);
        }
      }
    }
  }
}

// ---------------- RoPE in place on bf16 Q and K -----------------------------
__global__ __launch_bounds__(256)
void rope_bf16(u16* __restrict__ Qb, u16* __restrict__ Kb) {
  const int t = threadIdx.x;
  const int s = blockIdx.x * 4 + (t >> 6);
  const int d = t & 63;
  const int head = blockIdx.y, b = blockIdx.z;
  u16* row = (head < kNH)
      ? Qb + (((size_t)(b*kNH + head))*kS + s)*kHD
      : Kb + (((size_t)(b*kNKV + (head - kNH)))*kS + s)*kHD;
  const float inv_freq = powf(10000.0f, -(float)d * (1.0f/64.0f));   // accurate
  float sn, c; sincosf((float)s * inv_freq, &sn, &c);
  const float x1 = bf2f(row[d]), x2 = bf2f(row[d + 64]);
  row[d]      = f2bf(x1*c - x2*sn);
  row[d + 64] = f2bf(x2*c + x1*sn);
}

// ---------------- Flash attention, bf16 MFMA --------------------------------
// Block: 64 q-rows of one (b,h); 4 waves, wave w owns q-rows [16w,16w+16).
// K-tiles of 64. Padded LDS strides -> <=2-way bank conflicts on frag reads.
__global__ __launch_bounds__(256)
void flash_mfma(const u16* __restrict__ Qb, const u16* __restrict__ Kb,
                const u16* __restrict__ Vbt, u16* __restrict__ ctx) {
  __shared__ u16 Qs[64*136];
  __shared__ u16 Ks[64*136];
  __shared__ u16 Vts[128*72];   // [d][k] (V already transposed in memory)
  __shared__ u16 Ps[64*72];
  const int t = threadIdx.x, w = t >> 6, lane = t & 63;
  const int quad = lane >> 4, cl = lane & 15;
  const int qt = gridDim.x - 1 - blockIdx.x;          // heavy blocks first
  const int q0 = qt * 64;
  const int bh = blockIdx.y, b = bh >> 4, h = bh & 15, hk = h >> 2;
  const u16* Qg = Qb  + ((size_t)bh*kS + q0)*kHD;
  const u16* Kg = Kb  + ((size_t)(b*kNKV + hk))*kS*kHD;
  const u16* Vg = Vbt + ((size_t)(b*kNKV + hk))*kHD*kS;

#pragma unroll
  for (int it = 0; it < 4; ++it) {                    // stage Q once: 64x128
    const int c = t + it*256, r = c >> 4, c8 = c & 15;
    *(uint4*)(Qs + r*136 + c8*8) = *(const uint4*)(Qg + r*kHD + c8*8);
  }

  float m_[4], l_[4];
  f32x4 o[8];
#pragma unroll
  for (int r = 0; r < 4; ++r) { m_[r] = -1e30f; l_[r] = 0.f; }
#pragma unroll
  for (int dt = 0; dt < 8; ++dt) o[dt] = f32x4{0.f, 0.f, 0.f, 0.f};

  const int nt = qt + 1;
  for (int kt = 0; kt < nt; ++kt) {
    const int k0 = kt * 64;
    __syncthreads();                                  // prev PV reads done
#pragma unroll
    for (int it = 0; it < 4; ++it) {                  // K-tile 64x128
      const int c = t + it*256, r = c >> 4, c8 = c & 15;
      *(uint4*)(Ks + r*136 + c8*8) = *(const uint4*)(Kg + (size_t)(k0 + r)*kHD + c8*8);
    }
#pragma unroll
    for (int it = 0; it < 4; ++it) {                  // V-tile 128 d x 64 k
      const int c = t + it*256, d = c >> 3, c8 = c & 7;
      *(uint4*)(Vts + d*72 + c8*8) = *(const uint4*)(Vg + (size_t)d*kS + k0 + c8*8);
    }
    __syncthreads();

    f32x4 sacc[4];
#pragma unroll
    for (int j = 0; j < 4; ++j) sacc[j] = f32x4{0.f, 0.f, 0.f, 0.f};
#pragma unroll
    for (int dk = 0; dk < 4; ++dk) {
      const bf16x8 a = *(const bf16x8*)(Qs + (w*16 + cl)*136 + dk*32 + quad*8);
#pragma unroll
      for (int j = 0; j < 4; ++j) {
        const bf16x8 kb = *(const bf16x8*)(Ks + (j*16 + cl)*136 + dk*32 + quad*8);
        sacc[j] = __builtin_amdgcn_mfma_f32_16x16x32_bf16(a, kb, sacc[j], 0, 0, 0);
      }
    }
    // ---- online softmax (C layout: row=16w+quad*4+r, col=k0+16j+cl) ----
    const bool diag = (kt == nt - 1);
    float s[4][4], mt[4];
#pragma unroll
    for (int r = 0; r < 4; ++r) mt[r] = m_[r];
#pragma unroll
    for (int j = 0; j < 4; ++j)
#pragma unroll
      for (int r = 0; r < 4; ++r) {
        float sv = sacc[j][r] * kScale;
        if (diag && (k0 + j*16 + cl > q0 + w*16 + quad*4 + r)) sv = -1e30f;
        s[j][r] = sv;
        mt[r] = fmaxf(mt[r], sv);
      }
#pragma unroll
    for (int off = 1; off < 16; off <<= 1)
#pragma unroll
      for (int r = 0; r < 4; ++r) mt[r] = fmaxf(mt[r], __shfl_xor(mt[r], off, 64));
    float alpha[4];
#pragma unroll
    for (int r = 0; r < 4; ++r) { alpha[r] = __expf(m_[r] - mt[r]); m_[r] = mt[r]; }
    float ps[4] = {0.f, 0.f, 0.f, 0.f};
#pragma unroll
    for (int j = 0; j < 4; ++j)
#pragma unroll
      for (int r = 0; r < 4; ++r) {
        const float p = __expf(s[j][r] - m_[r]);
        ps[r] += p;
        Ps[(w*16 + quad*4 + r)*72 + j*16 + cl] = f2bf(p);   // wave-private rows
      }
#pragma unroll
    for (int off = 1; off < 16; off <<= 1)
#pragma unroll
      for (int r = 0; r < 4; ++r) ps[r] += __shfl_xor(ps[r], off, 64);
#pragma unroll
    for (int r = 0; r < 4; ++r) l_[r] = l_[r]*alpha[r] + ps[r];
#pragma unroll
    for (int dt = 0; dt < 8; ++dt)
#pragma unroll
      for (int r = 0; r < 4; ++r) o[dt][r] *= alpha[r];
    // ---- PV: O[16 x 128] += P[16 x 64] @ V[64 x 128] (per wave) ----
#pragma unroll
    for (int ks = 0; ks < 2; ++ks) {
      const bf16x8 ap = *(const bf16x8*)(Ps + (w*16 + cl)*72 + ks*32 + quad*8);
#pragma unroll
      for (int dt = 0; dt < 8; ++dt) {
        const bf16x8 bv = *(const bf16x8*)(Vts + (dt*16 + cl)*72 + ks*32 + quad*8);
        o[dt] = __builtin_amdgcn_mfma_f32_16x16x32_bf16(ap, bv, o[dt], 0, 0, 0);
      }
    }
  }
  // epilogue: ctx[b][q][h*128+d] bf16
#pragma unroll
  for (int r = 0; r < 4; ++r) {
    const float inv = 1.0f / l_[r];
    const int q = q0 + w*16 + quad*4 + r;
    u16* orow = ctx + ((size_t)(b*kS + q))*(kNH*kHD) + h*kHD;
#pragma unroll
    for (int dt = 0; dt < 8; ++dt)
      orow[dt*16 + cl] = f2bf(o[dt][r] * inv);
  }
}

// ---------------- O-projection: bf16 MFMA GEMM, fp32 out --------------------
__global__ __launch_bounds__(256)
void oproj_mfma(const u16* __restrict__ A, const u16* __restrict__ W,
                float* __restrict__ C) {
  __shared__ u16 At[128*32];
  __shared__ u16 Bt[128*32];
  const int t = threadIdx.x, w = t >> 6, lane = t & 63;
  const int quad = lane >> 4, cl = lane & 15;
  const int wm = w >> 1, wn = w & 1;
  const int m0 = blockIdx.x * 128, n0 = blockIdx.y * 128;
  const int srow = lane >> 2, scol = (lane & 3) * 8;

  f32x4 acc[4][4];
#pragma unroll
  for (int i = 0; i < 4; ++i)
#pragma unroll
    for (int j = 0; j < 4; ++j) acc[i][j] = f32x4{0.f, 0.f, 0.f, 0.f};

  for (int k0 = 0; k0 < kHid; k0 += 32) {
    __syncthreads();
#pragma unroll
    for (int c = 0; c < 2; ++c) {
      const int rr = w*32 + c*16;
      gl_lds16(A + (size_t)(m0 + rr + srow)*kHid + k0 + scol, At + rr*32);
      gl_lds16(W + (size_t)(n0 + rr + srow)*kHid + k0 + scol, Bt + rr*32);
    }
    __syncthreads();
    bf16x8 a[4], b[4];
#pragma unroll
    for (int i = 0; i < 4; ++i)
      a[i] = *(const bf16x8*)(At + (wm*64 + i*16 + cl)*32 + quad*8);
#pragma unroll
    for (int j = 0; j < 4; ++j)
      b[j] = *(const bf16x8*)(Bt + (wn*64 + j*16 + cl)*32 + quad*8);
#pragma unroll
    for (int i = 0; i < 4; ++i)
#pragma unroll
      for (int j = 0; j < 4; ++j)
        acc[i][j] = __builtin_amdgcn_mfma_f32_16x16x32_bf16(a[i], b[j], acc[i][j], 0, 0, 0);
  }
#pragma unroll
  for (int i = 0; i < 4; ++i)
#pragma unroll
    for (int r = 0; r < 4; ++r) {
      const int m = m0 + wm*64 + i*16 + quad*4 + r;
#pragma unroll
      for (int j = 0; j < 4; ++j)
        C[(size_t)m*kHid + (n0 + wn*64 + j*16 + cl)] = acc[i][j][r];
    }
}

extern "C" void kernel_launch(void* const* d_in, const int* in_sizes, int n_in,
                              void* d_out, int out_size, void* d_ws, size_t ws_size,
                              hipStream_t stream) {
  const float* hs  = (const float*)d_in[0];
  // d_in[1] = attention_mask: causal by construction, not read
  const float* q_w = (const float*)d_in[2];
  const float* q_b = (const float*)d_in[3];
  const float* k_w = (const float*)d_in[4];
  const float* k_b = (const float*)d_in[5];
  const float* v_w = (const float*)d_in[6];
  const float* v_b = (const float*)d_in[7];
  const float* o_w = (const float*)d_in[8];

  // ws layout (u16 elements). ctx_b aliases hs_b: hs dead after qkv gemm.
  u16* wsu  = (u16*)d_ws;
  u16* hs_b = wsu;                                   // 8M
  u16* ctx_b = wsu;                                  // 8M (after flash)
  u16* qw_b = wsu + 8388608;                         // 4M
  u16* kw_b = wsu + 12582912;                        // 1M
  u16* vw_b = wsu + 13631488;                        // 1M
  u16* ow_b = wsu + 14680064;                        // 4M
  u16* Kb   = wsu + 18874368;                        // 2M
  u16* Vbt  = wsu + 20971520;                        // 2M  -> 44 MB total
  u16* Qb   = (u16*)d_out;                           // 8M bf16 in 32MB d_out

  conv_bf16<<<4096, 256, 0, stream>>>(hs,  hs_b, 1048576);
  conv_bf16<<<2048, 256, 0, stream>>>(q_w, qw_b, 524288);
  conv_bf16<<<512,  256, 0, stream>>>(k_w, kw_b, 131072);
  conv_bf16<<<512,  256, 0, stream>>>(v_w, vw_b, 131072);
  conv_bf16<<<2048, 256, 0, stream>>>(o_w, ow_b, 524288);

  qkv_mfma<<<dim3(32, 24), 256, 0, stream>>>(hs_b, qw_b, kw_b, vw_b,
                                             q_b, k_b, v_b, Qb, Kb, Vbt);
  rope_bf16<<<dim3(512, 20, 2), 256, 0, stream>>>(Qb, Kb);
  flash_mfma<<<dim3(32, 32), 256, 0, stream>>>(Qb, Kb, Vbt, ctx_b);
  oproj_mfma<<<dim3(32, 16), 256, 0, stream>>>(ctx_b, ow_b, (float*)d_out);
}

// Round 3
// 510.225 us; speedup vs baseline: 4.7985x; 1.0885x over previous
//
#include <hip/hip_runtime.h>
#include <math.h>

typedef __attribute__((ext_vector_type(8))) short bf16x8;   // 8 bf16 in 4 VGPRs
typedef __attribute__((ext_vector_type(4))) float f32x4;
typedef unsigned short u16;

constexpr int kB = 2, kS = 2048, kHid = 2048, kNH = 16, kNKV = 4, kHD = 128;
constexpr float kScale = 0.08838834764831845f;   // 1/sqrt(128)

__device__ __forceinline__ u16 f2bf(float x) {
  union { float f; unsigned int u; } v; v.f = x;
  unsigned int r = v.u + 0x7fffu + ((v.u >> 16) & 1u);   // RNE
  return (u16)(r >> 16);
}
__device__ __forceinline__ float bf2f(u16 b) {
  union { unsigned int u; float f; } v; v.u = ((unsigned int)b) << 16;
  return v.f;
}
__device__ __forceinline__ void gl_lds16(const u16* g, u16* l) {
  __builtin_amdgcn_global_load_lds((const __attribute__((address_space(1))) void*)g,
                                   (__attribute__((address_space(3))) void*)l, 16, 0, 0);
}

// ---------------- fp32 -> bf16 conversion, 8 elements/thread ----------------
__global__ __launch_bounds__(256)
void conv_bf16(const float* __restrict__ s, u16* __restrict__ d, int n8) {
  int i = blockIdx.x * 256 + threadIdx.x;
  if (i >= n8) return;
  const float4* s4 = (const float4*)s;
  float4 a = s4[2*i], b = s4[2*i + 1];
  __align__(16) u16 tmp[8] = {f2bf(a.x), f2bf(a.y), f2bf(a.z), f2bf(a.w),
                              f2bf(b.x), f2bf(b.y), f2bf(b.z), f2bf(b.w)};
  *(uint4*)(d + 8*(size_t)i) = *(const uint4*)tmp;
}

// ---------------- QKV projection: bf16 MFMA GEMM, 128x128 tile, BK=32 -------
__global__ __launch_bounds__(256)
void qkv_mfma(const u16* __restrict__ hs_b,
              const u16* __restrict__ qw_b, const u16* __restrict__ kw_b,
              const u16* __restrict__ vw_b,
              const float* __restrict__ q_bias, const float* __restrict__ k_bias,
              const float* __restrict__ v_bias,
              u16* __restrict__ Qb, u16* __restrict__ Kb, u16* __restrict__ Vbt) {
  __shared__ u16 At[128*32];
  __shared__ u16 Bt[128*32];
  const int t = threadIdx.x, w = t >> 6, lane = t & 63;
  const int quad = lane >> 4, cl = lane & 15;
  const int wm = w >> 1, wn = w & 1;
  const int m0 = blockIdx.x * 128, n0 = blockIdx.y * 128;
  const u16* wbase; int nr0;                 // region (128-aligned boundaries)
  if (n0 < 2048)      { wbase = qw_b; nr0 = n0; }
  else if (n0 < 2560) { wbase = kw_b; nr0 = n0 - 2048; }
  else                { wbase = vw_b; nr0 = n0 - 2560; }

  const int srow = lane >> 2;
  const int scol = (lane & 3) * 8;

  f32x4 acc[4][4];
#pragma unroll
  for (int i = 0; i < 4; ++i)
#pragma unroll
    for (int j = 0; j < 4; ++j) acc[i][j] = f32x4{0.f, 0.f, 0.f, 0.f};

  for (int k0 = 0; k0 < kHid; k0 += 32) {
    __syncthreads();
#pragma unroll
    for (int c = 0; c < 2; ++c) {
      const int rr = w*32 + c*16;
      gl_lds16(hs_b  + (size_t)(m0 + rr + srow)*kHid + k0 + scol, At + rr*32);
      gl_lds16(wbase + (size_t)(nr0 + rr + srow)*kHid + k0 + scol, Bt + rr*32);
    }
    __syncthreads();
    bf16x8 a[4], b[4];
#pragma unroll
    for (int i = 0; i < 4; ++i)
      a[i] = *(const bf16x8*)(At + (wm*64 + i*16 + cl)*32 + quad*8);
#pragma unroll
    for (int j = 0; j < 4; ++j)
      b[j] = *(const bf16x8*)(Bt + (wn*64 + j*16 + cl)*32 + quad*8);
#pragma unroll
    for (int i = 0; i < 4; ++i)
#pragma unroll
      for (int j = 0; j < 4; ++j)
        acc[i][j] = __builtin_amdgcn_mfma_f32_16x16x32_bf16(a[i], b[j], acc[i][j], 0, 0, 0);
  }
#pragma unroll
  for (int i = 0; i < 4; ++i) {
#pragma unroll
    for (int r = 0; r < 4; ++r) {
      const int m = m0 + wm*64 + i*16 + quad*4 + r;
      const int bi = m >> 11, s = m & (kS - 1);
#pragma unroll
      for (int j = 0; j < 4; ++j) {
        const int n = n0 + wn*64 + j*16 + cl;
        float v = acc[i][j][r];
        if (n < 2048) {
          v += q_bias[n];
          Qb[(((size_t)(bi*kNH + (n >> 7)))*kS + s)*kHD + (n & 127)] = f2bf(v);
        } else if (n < 2560) {
          const int nk = n - 2048; v += k_bias[nk];
          Kb[(((size_t)(bi*kNKV + (nk >> 7)))*kS + s)*kHD + (nk & 127)] = f2bf(v);
        } else {
          const int nk = n - 2560; v += v_bias[nk];
          Vbt[(((size_t)(bi*kNKV + (nk >> 7)))*kHD + (nk & 127))*kS + s] = f2bf(v);
        }
      }
    }
  }
}

// ---------------- RoPE in place on bf16 Q and K -----------------------------
__global__ __launch_bounds__(256)
void rope_bf16(u16* __restrict__ Qb, u16* __restrict__ Kb) {
  const int t = threadIdx.x;
  const int s = blockIdx.x * 4 + (t >> 6);
  const int d = t & 63;
  const int head = blockIdx.y, b = blockIdx.z;
  u16* row = (head < kNH)
      ? Qb + (((size_t)(b*kNH + head))*kS + s)*kHD
      : Kb + (((size_t)(b*kNKV + (head - kNH)))*kS + s)*kHD;
  const float inv_freq = powf(10000.0f, -(float)d * (1.0f/64.0f));
  float sn, c; sincosf((float)s * inv_freq, &sn, &c);
  const float x1 = bf2f(row[d]), x2 = bf2f(row[d + 64]);
  row[d]      = f2bf(x1*c - x2*sn);
  row[d + 64] = f2bf(x2*c + x1*sn);
}

// ---------------- Flash attention v3: Q in regs, 32 q-rows/wave, prefetch ---
// Block = 4 waves x 32 q-rows = 128 q-rows of one (b,h). K-tiles of 64.
// Q A-frags live in VGPRs (loaded once). Next K/V tile prefetched into VGPRs
// during compute, written to LDS after the barrier (global latency hidden).
__global__ __launch_bounds__(256, 2)
void flash_mfma(const u16* __restrict__ Qb, const u16* __restrict__ Kb,
                const u16* __restrict__ Vbt, u16* __restrict__ ctx) {
  __shared__ u16 Ks[64*136];    // [k-row][d],  +8 pad: frag reads conflict-free
  __shared__ u16 Vts[128*72];   // [d][k-col],  +8 pad
  __shared__ u16 Ps[128*72];    // [q-row][k-col], wave-private rows
  const int t = threadIdx.x, w = t >> 6, lane = t & 63;
  const int quad = lane >> 4, cl = lane & 15;
  const int qbx = gridDim.x - 1 - blockIdx.x;         // heavy blocks first
  const int q0 = qbx * 128;
  const int qw = q0 + w*32;                           // this wave's first q-row
  const int bh = blockIdx.y, b = bh >> 4, h = bh & 15, hk = h >> 2;
  const u16* Qg = Qb  + ((size_t)bh*kS + q0)*kHD;
  const u16* Kg = Kb  + ((size_t)(b*kNKV + hk))*kS*kHD;
  const u16* Vg = Vbt + ((size_t)(b*kNKV + hk))*kHD*kS;

  // Q fragments in registers: rows w*32+rb*16+cl, k = dk*32+quad*8
  bf16x8 qf[2][4];
#pragma unroll
  for (int rb = 0; rb < 2; ++rb)
#pragma unroll
    for (int dk = 0; dk < 4; ++dk)
      qf[rb][dk] = *(const bf16x8*)(Qg + (size_t)(w*32 + rb*16 + cl)*kHD + dk*32 + quad*8);

  float m_[2][4], l_[2][4];
  f32x4 o[2][8];
#pragma unroll
  for (int rb = 0; rb < 2; ++rb) {
#pragma unroll
    for (int r = 0; r < 4; ++r) { m_[rb][r] = -1e30f; l_[rb][r] = 0.f; }
#pragma unroll
    for (int dt = 0; dt < 8; ++dt) o[rb][dt] = f32x4{0.f, 0.f, 0.f, 0.f};
  }

  // staging split: thread t owns 4 uint4 of K-tile and 4 of V-tile
  const int kr  = t >> 4,       kc8 = t & 15;   // K: row kr(+16*it), 16B chunk kc8
  const int vd  = t >> 3,       vc8 = t & 7;    // V: d-row vd(+32*it), chunk vc8

  const int nt = 2*qbx + 2;                     // block-uniform k-tile count
  uint4 kpre[4], vpre[4];
#pragma unroll
  for (int it = 0; it < 4; ++it) {              // prefetch tile 0
    kpre[it] = *(const uint4*)(Kg + (size_t)(it*16 + kr)*kHD + kc8*8);
    vpre[it] = *(const uint4*)(Vg + (size_t)(it*32 + vd)*kS  + vc8*8);
  }

  for (int kt = 0; kt < nt; ++kt) {
    const int k0 = kt * 64;
    __syncthreads();                            // prev tile frag reads done
#pragma unroll
    for (int it = 0; it < 4; ++it) {
      *(uint4*)(Ks  + (it*16 + kr)*136 + kc8*8) = kpre[it];
      *(uint4*)(Vts + (it*32 + vd)*72  + vc8*8) = vpre[it];
    }
    __syncthreads();
    if (kt + 1 < nt) {                          // prefetch next tile (hidden)
      const int kn = k0 + 64;
#pragma unroll
      for (int it = 0; it < 4; ++it) {
        kpre[it] = *(const uint4*)(Kg + (size_t)(kn + it*16 + kr)*kHD + kc8*8);
        vpre[it] = *(const uint4*)(Vg + (size_t)(it*32 + vd)*kS + kn + vc8*8);
      }
    }

    // ---- QK^T: S[32 x 64] per wave ----
    f32x4 sacc[2][4];
#pragma unroll
    for (int rb = 0; rb < 2; ++rb)
#pragma unroll
      for (int j = 0; j < 4; ++j) sacc[rb][j] = f32x4{0.f, 0.f, 0.f, 0.f};
#pragma unroll
    for (int dk = 0; dk < 4; ++dk) {
      bf16x8 kf[4];
#pragma unroll
      for (int j = 0; j < 4; ++j)
        kf[j] = *(const bf16x8*)(Ks + (j*16 + cl)*136 + dk*32 + quad*8);
#pragma unroll
      for (int rb = 0; rb < 2; ++rb)
#pragma unroll
        for (int j = 0; j < 4; ++j)
          sacc[rb][j] = __builtin_amdgcn_mfma_f32_16x16x32_bf16(qf[rb][dk], kf[j], sacc[rb][j], 0, 0, 0);
    }

    // ---- online softmax per row-block (C layout: row=quad*4+r, col=16j+cl) --
    const bool diag = (k0 + 63 > qw);           // any masking needed this tile
#pragma unroll
    for (int rb = 0; rb < 2; ++rb) {
      float s[4][4], mt[4];
#pragma unroll
      for (int r = 0; r < 4; ++r) mt[r] = m_[rb][r];
#pragma unroll
      for (int j = 0; j < 4; ++j)
#pragma unroll
        for (int r = 0; r < 4; ++r) {
          float sv = sacc[rb][j][r] * kScale;
          if (diag && (k0 + j*16 + cl > qw + rb*16 + quad*4 + r)) sv = -1e30f;
          s[j][r] = sv;
          mt[r] = fmaxf(mt[r], sv);
        }
#pragma unroll
      for (int off = 1; off < 16; off <<= 1)
#pragma unroll
        for (int r = 0; r < 4; ++r) mt[r] = fmaxf(mt[r], __shfl_xor(mt[r], off, 64));
      float alpha[4];
#pragma unroll
      for (int r = 0; r < 4; ++r) { alpha[r] = __expf(m_[rb][r] - mt[r]); m_[rb][r] = mt[r]; }
      float ps[4] = {0.f, 0.f, 0.f, 0.f};
#pragma unroll
      for (int j = 0; j < 4; ++j)
#pragma unroll
        for (int r = 0; r < 4; ++r) {
          float p = __expf(s[j][r] - m_[rb][r]);
          if (s[j][r] <= -1e29f) p = 0.f;
          ps[r] += p;
          Ps[(w*32 + rb*16 + quad*4 + r)*72 + j*16 + cl] = f2bf(p);
        }
#pragma unroll
      for (int off = 1; off < 16; off <<= 1)
#pragma unroll
        for (int r = 0; r < 4; ++r) ps[r] += __shfl_xor(ps[r], off, 64);
#pragma unroll
      for (int r = 0; r < 4; ++r) l_[rb][r] = l_[rb][r]*alpha[r] + ps[r];
#pragma unroll
      for (int dt = 0; dt < 8; ++dt)
#pragma unroll
        for (int r = 0; r < 4; ++r) o[rb][dt][r] *= alpha[r];
    }

    // ---- PV: O[32 x 128] += P[32 x 64] @ V[64 x 128] (per wave) ----
#pragma unroll
    for (int ks = 0; ks < 2; ++ks) {
      bf16x8 pf[2];
#pragma unroll
      for (int rb = 0; rb < 2; ++rb)
        pf[rb] = *(const bf16x8*)(Ps + (w*32 + rb*16 + cl)*72 + ks*32 + quad*8);
#pragma unroll
      for (int dt = 0; dt < 8; ++dt) {
        const bf16x8 vf = *(const bf16x8*)(Vts + (dt*16 + cl)*72 + ks*32 + quad*8);
#pragma unroll
        for (int rb = 0; rb < 2; ++rb)
          o[rb][dt] = __builtin_amdgcn_mfma_f32_16x16x32_bf16(pf[rb], vf, o[rb][dt], 0, 0, 0);
      }
    }
  }

  // epilogue: ctx[b][q][h*128+d] bf16
#pragma unroll
  for (int rb = 0; rb < 2; ++rb)
#pragma unroll
    for (int r = 0; r < 4; ++r) {
      const float inv = 1.0f / l_[rb][r];
      const int q = qw + rb*16 + quad*4 + r;
      u16* orow = ctx + ((size_t)(b*kS + q))*(kNH*kHD) + h*kHD;
#pragma unroll
      for (int dt = 0; dt < 8; ++dt)
        orow[dt*16 + cl] = f2bf(o[rb][dt][r] * inv);
    }
}

// ---------------- O-projection: bf16 MFMA GEMM, fp32 out --------------------
__global__ __launch_bounds__(256)
void oproj_mfma(const u16* __restrict__ A, const u16* __restrict__ W,
                float* __restrict__ C) {
  __shared__ u16 At[128*32];
  __shared__ u16 Bt[128*32];
  const int t = threadIdx.x, w = t >> 6, lane = t & 63;
  const int quad = lane >> 4, cl = lane & 15;
  const int wm = w >> 1, wn = w & 1;
  const int m0 = blockIdx.x * 128, n0 = blockIdx.y * 128;
  const int srow = lane >> 2, scol = (lane & 3) * 8;

  f32x4 acc[4][4];
#pragma unroll
  for (int i = 0; i < 4; ++i)
#pragma unroll
    for (int j = 0; j < 4; ++j) acc[i][j] = f32x4{0.f, 0.f, 0.f, 0.f};

  for (int k0 = 0; k0 < kHid; k0 += 32) {
    __syncthreads();
#pragma unroll
    for (int c = 0; c < 2; ++c) {
      const int rr = w*32 + c*16;
      gl_lds16(A + (size_t)(m0 + rr + srow)*kHid + k0 + scol, At + rr*32);
      gl_lds16(W + (size_t)(n0 + rr + srow)*kHid + k0 + scol, Bt + rr*32);
    }
    __syncthreads();
    bf16x8 a[4], b[4];
#pragma unroll
    for (int i = 0; i < 4; ++i)
      a[i] = *(const bf16x8*)(At + (wm*64 + i*16 + cl)*32 + quad*8);
#pragma unroll
    for (int j = 0; j < 4; ++j)
      b[j] = *(const bf16x8*)(Bt + (wn*64 + j*16 + cl)*32 + quad*8);
#pragma unroll
    for (int i = 0; i < 4; ++i)
#pragma unroll
      for (int j = 0; j < 4; ++j)
        acc[i][j] = __builtin_amdgcn_mfma_f32_16x16x32_bf16(a[i], b[j], acc[i][j], 0, 0, 0);
  }
#pragma unroll
  for (int i = 0; i < 4; ++i)
#pragma unroll
    for (int r = 0; r < 4; ++r) {
      const int m = m0 + wm*64 + i*16 + quad*4 + r;
#pragma unroll
      for (int j = 0; j < 4; ++j)
        C[(size_t)m*kHid + (n0 + wn*64 + j*16 + cl)] = acc[i][j][r];
    }
}

extern "C" void kernel_launch(void* const* d_in, const int* in_sizes, int n_in,
                              void* d_out, int out_size, void* d_ws, size_t ws_size,
                              hipStream_t stream) {
  const float* hs  = (const float*)d_in[0];
  // d_in[1] = attention_mask: causal by construction, not read
  const float* q_w = (const float*)d_in[2];
  const float* q_b = (const float*)d_in[3];
  const float* k_w = (const float*)d_in[4];
  const float* k_b = (const float*)d_in[5];
  const float* v_w = (const float*)d_in[6];
  const float* v_b = (const float*)d_in[7];
  const float* o_w = (const float*)d_in[8];

  u16* wsu  = (u16*)d_ws;
  u16* hs_b = wsu;                                   // 8M
  u16* ctx_b = wsu;                                  // 8M (after flash; hs dead)
  u16* qw_b = wsu + 8388608;                         // 4M
  u16* kw_b = wsu + 12582912;                        // 1M
  u16* vw_b = wsu + 13631488;                        // 1M
  u16* ow_b = wsu + 14680064;                        // 4M
  u16* Kb   = wsu + 18874368;                        // 2M
  u16* Vbt  = wsu + 20971520;                        // 2M  -> 44 MB total
  u16* Qb   = (u16*)d_out;                           // 8M bf16 in 32MB d_out

  conv_bf16<<<4096, 256, 0, stream>>>(hs,  hs_b, 1048576);
  conv_bf16<<<2048, 256, 0, stream>>>(q_w, qw_b, 524288);
  conv_bf16<<<512,  256, 0, stream>>>(k_w, kw_b, 131072);
  conv_bf16<<<512,  256, 0, stream>>>(v_w, vw_b, 131072);
  conv_bf16<<<2048, 256, 0, stream>>>(o_w, ow_b, 524288);

  qkv_mfma<<<dim3(32, 24), 256, 0, stream>>>(hs_b, qw_b, kw_b, vw_b,
                                             q_b, k_b, v_b, Qb, Kb, Vbt);
  rope_bf16<<<dim3(512, 20, 2), 256, 0, stream>>>(Qb, Kb);
  flash_mfma<<<dim3(16, 32), 256, 0, stream>>>(Qb, Kb, Vbt, ctx_b);
  oproj_mfma<<<dim3(32, 16), 256, 0, stream>>>(ctx_b, ow_b, (float*)d_out);
}